// Round 2
// baseline (341.730 us; speedup 1.0000x reference)
//
#include <hip/hip_runtime.h>
#include <hip/hip_bf16.h>

typedef __attribute__((ext_vector_type(8))) short short8;
typedef __attribute__((ext_vector_type(4))) float floatx4;

__device__ __forceinline__ float sigm(float x) { return 1.0f / (1.0f + __expf(-x)); }

__device__ __forceinline__ unsigned short f2bf(float v) {
  union { __hip_bfloat16 h; unsigned short u; } cv;
  cv.h = __float2bfloat16(v);
  return cv.u;
}

// ---------------- prep: fold ia/im/bias into padded bf16 weights ----------------
// Combined channel c (0..170): c<18 -> det row c (scaled by im, bias im*(b + W.ia));
//                              c>=18 -> kpt row c-18 (bias bk). Rows 171..175 zero.
struct PrepArgs {
  const float *w, *b, *im, *ia, *wk, *bk;
  unsigned short* Wp;
  float* bias;
  int C;
};

__global__ void prep_kernel(PrepArgs A0, PrepArgs A1, PrepArgs A2) {
  PrepArgs A = (blockIdx.y == 0) ? A0 : (blockIdx.y == 1) ? A1 : A2;
  const int n = blockIdx.x;   // 0..175
  const int t = threadIdx.x;  // 0..63 (one wave)
  const int C = A.C;
  unsigned short* wrow = A.Wp + (size_t)n * C;
  if (n >= 171) {
    for (int k = t; k < C; k += 64) wrow[k] = 0;
    if (t == 0) A.bias[n] = 0.0f;
    return;
  }
  if (n < 18) {
    const float* src = A.w + (size_t)n * C;
    const float sc = A.im[n];
    float dot = 0.0f;
    for (int k = t; k < C; k += 64) {
      float v = src[k];
      dot += v * A.ia[k];
      wrow[k] = f2bf(v * sc);
    }
#pragma unroll
    for (int off = 32; off > 0; off >>= 1) dot += __shfl_down(dot, off);
    if (t == 0) A.bias[n] = sc * (A.b[n] + dot);
  } else {
    const float* src = A.wk + (size_t)(n - 18) * C;
    for (int k = t; k < C; k += 64) wrow[k] = f2bf(src[k]);
    if (t == 0) A.bias[n] = A.bk[n - 18];
  }
}

// ---------------- barrier-free fused GEMM (bf16 MFMA) + decode ----------------
// Block = 128 m-rows; 4 waves, each owning 32 rows x 176 cols.
// A: wave-private double-buffered LDS staging (no __syncthreads in K-loop).
// B: gathered straight from global (L2-resident), line-coalesced per fragment.
#define LDS_BYTES 36864  // 4 waves * 2 bufs * 32*72*2 B; epilogue 32*180*4 reuses it

template <int SC, int C, int HW, int W>
__device__ __forceinline__ void gemm_decode(const float* __restrict__ feat,
                                            const unsigned short* __restrict__ Wp,
                                            const float* __restrict__ bias,
                                            float* __restrict__ out, int tile, char* smem) {
  constexpr float STRD = (SC == 0) ? 8.0f : (SC == 1) ? 16.0f : 32.0f;
  constexpr int ZOFF = (SC == 0) ? 0 : (SC == 1) ? 19200 : 24000;
  constexpr int I = C / 64;

  const int t = threadIdx.x;
  const int lane = t & 63;
  const int wv = t >> 6;
  const int l15 = lane & 15;
  const int quad = lane >> 4;

  unsigned short* Alds = (unsigned short*)smem;  // [wave][buf][32][72] bf16
  float* Elds = (float*)smem;                    // epilogue [32][180] fp32 (reuse)

  // staging: lane stages row r = lane&31, k-half kh = lane>>5 (32 k's each)
  const int r = lane & 31;
  const int kh = lane >> 5;
  const int mG = tile * 128 + wv * 32 + r;
  const int bA = mG / HW;
  const int pA = mG - bA * HW;
  const float* gL = feat + ((size_t)bA * C + kh * 32) * (size_t)HW + pA;

  floatx4 acc[2][11];
#pragma unroll
  for (int mi = 0; mi < 2; ++mi)
#pragma unroll
    for (int nj = 0; nj < 11; ++nj) acc[mi][nj] = (floatx4){0.f, 0.f, 0.f, 0.f};

  const unsigned short* bP = Wp + (size_t)l15 * C + quad * 8;
  unsigned short* wD = Alds + wv * 4608 + r * 72 + kh * 32;     // + pb*2304
  const unsigned short* aB = Alds + wv * 4608 + l15 * 72 + quad * 8;  // + pb*2304

  float v[32];
  auto loadA = [&](int it) {
    const float* g = gL + (size_t)it * 64 * HW;
#pragma unroll
    for (int kk = 0; kk < 32; ++kk) v[kk] = g[(size_t)kk * HW];
  };
  auto writeA = [&](int pb) {
    unsigned short* d = wD + pb * 2304;
#pragma unroll
    for (int c8 = 0; c8 < 4; ++c8) {
      short8 s;
#pragma unroll
      for (int j = 0; j < 8; ++j) s[j] = (short)f2bf(v[c8 * 8 + j]);
      *(short8*)(d + c8 * 8) = s;
    }
  };
  auto mfmaStep = [&](int it) {
    const int pb = it & 1;
    const unsigned short* a = aB + pb * 2304;
    short8 af[2][2];
#pragma unroll
    for (int mi = 0; mi < 2; ++mi)
#pragma unroll
      for (int h = 0; h < 2; ++h) af[mi][h] = *(const short8*)(a + mi * 1152 + h * 32);
    const unsigned short* bI = bP + it * 64;
#pragma unroll
    for (int nj = 0; nj < 11; ++nj) {
      short8 b0 = *(const short8*)(bI + (size_t)nj * 16 * C);
      short8 b1 = *(const short8*)(bI + (size_t)nj * 16 * C + 32);
      acc[0][nj] = __builtin_amdgcn_mfma_f32_16x16x32_bf16(af[0][0], b0, acc[0][nj], 0, 0, 0);
      acc[1][nj] = __builtin_amdgcn_mfma_f32_16x16x32_bf16(af[1][0], b0, acc[1][nj], 0, 0, 0);
      acc[0][nj] = __builtin_amdgcn_mfma_f32_16x16x32_bf16(af[0][1], b1, acc[0][nj], 0, 0, 0);
      acc[1][nj] = __builtin_amdgcn_mfma_f32_16x16x32_bf16(af[1][1], b1, acc[1][nj], 0, 0, 0);
    }
  };

  // software-pipelined, barrier-free K-loop: next A-loads issue before MFMA section
  loadA(0);
#pragma unroll
  for (int it = 0; it < I - 1; ++it) {
    writeA(it & 1);
    loadA(it + 1);
    mfmaStep(it);
  }
  writeA((I - 1) & 1);
  mfmaStep(I - 1);

  // ---------------- epilogue: 4 chunks of 32 rows (one wave's acc each) ----------------
  float bj[11];
#pragma unroll
  for (int nj = 0; nj < 11; ++nj) bj[nj] = bias[nj * 16 + l15];

#pragma unroll
  for (int c = 0; c < 4; ++c) {
    __syncthreads();  // Elds free (main loop done / prev copyout done)
    if (wv == c) {
#pragma unroll
      for (int nj = 0; nj < 11; ++nj)
#pragma unroll
        for (int mi = 0; mi < 2; ++mi)
#pragma unroll
          for (int rr = 0; rr < 4; ++rr)
            Elds[(mi * 16 + quad * 4 + rr) * 180 + nj * 16 + l15] = acc[mi][nj][rr] + bj[nj];
    }
    __syncthreads();
    if (t < 192) {
      const int task = t >> 1, half = t & 1;
      const int row = task & 31, a = task >> 5;
      const int m = tile * 128 + c * 32 + row;
      const int bb = m / HW;
      const int p = m - bb * HW;
      const float fx = (float)(p % W);
      const float fy = (float)(p / W);
      float* L = Elds + row * 180 + a * 57;
      if (half == 0) {
        float aw, ah;
        if constexpr (SC == 0) {
          aw = (a == 0) ? 19.f : (a == 1) ? 44.f : 38.f;
          ah = (a == 0) ? 27.f : (a == 1) ? 40.f : 94.f;
        } else if constexpr (SC == 1) {
          aw = (a == 0) ? 96.f : (a == 1) ? 86.f : 180.f;
          ah = (a == 0) ? 68.f : (a == 1) ? 152.f : 137.f;
        } else {
          aw = (a == 0) ? 140.f : (a == 1) ? 303.f : 238.f;
          ah = (a == 0) ? 301.f : (a == 1) ? 264.f : 542.f;
        }
        float r0 = L[0], r1 = L[1], r2 = L[2], r3 = L[3], r4 = L[4], r5 = L[5];
        L[0] = (sigm(r0) * 2.f - 0.5f + fx) * STRD;
        L[1] = (sigm(r1) * 2.f - 0.5f + fy) * STRD;
        float tw = sigm(r2) * 2.f;
        L[2] = tw * tw * aw;
        float th = sigm(r3) * 2.f;
        L[3] = th * th * ah;
        L[4] = sigm(r4);
        L[5] = sigm(r5);
#pragma unroll
        for (int kp = 0; kp < 8; ++kp) {
          float kx = L[6 + 3 * kp], ky = L[7 + 3 * kp], kc = L[8 + 3 * kp];
          L[6 + 3 * kp] = (kx * 2.f - 0.5f + fx) * STRD;
          L[7 + 3 * kp] = (ky * 2.f - 0.5f + fy) * STRD;
          L[8 + 3 * kp] = sigm(kc);
        }
      } else {
#pragma unroll
        for (int kp = 8; kp < 17; ++kp) {
          float kx = L[6 + 3 * kp], ky = L[7 + 3 * kp], kc = L[8 + 3 * kp];
          L[6 + 3 * kp] = (kx * 2.f - 0.5f + fx) * STRD;
          L[7 + 3 * kp] = (ky * 2.f - 0.5f + fy) * STRD;
          L[8 + 3 * kp] = sigm(kc);
        }
      }
    }
    __syncthreads();
    for (int i = t; i < 96 * 57; i += 256) {
      int sr = i / 57;
      int j = i - sr * 57;
      int a = sr >> 5, row = sr & 31;
      int m = tile * 128 + c * 32 + row;
      int bb = m / HW;
      int p = m - bb * HW;
      out[((size_t)bb * 25200 + (size_t)(ZOFF + a * HW + p)) * 57 + j] =
          Elds[row * 180 + a * 57 + j];
    }
  }
}

__global__ __launch_bounds__(256, 2) void main_kernel(
    const float* __restrict__ f0, const float* __restrict__ f1, const float* __restrict__ f2,
    const unsigned short* __restrict__ Wp0, const unsigned short* __restrict__ Wp1,
    const unsigned short* __restrict__ Wp2, const float* __restrict__ b0,
    const float* __restrict__ b1, const float* __restrict__ b2, float* __restrict__ out) {
  __shared__ __align__(16) char smem[LDS_BYTES];
  const int bid = blockIdx.x;
  // longest blocks (scale 2, C=1024) first to amortize the tail
  if (bid < 50)
    gemm_decode<2, 1024, 400, 20>(f2, Wp2, b2, out, bid, smem);
  else if (bid < 250)
    gemm_decode<1, 512, 1600, 40>(f1, Wp1, b1, out, bid - 50, smem);
  else
    gemm_decode<0, 256, 6400, 80>(f0, Wp0, b0, out, bid - 250, smem);
}

extern "C" void kernel_launch(void* const* d_in, const int* in_sizes, int n_in, void* d_out,
                              int out_size, void* d_ws, size_t ws_size, hipStream_t stream) {
  const float *f[3], *ia[3], *w[3], *b[3], *im[3], *wk[3], *bk[3];
  for (int s = 0; s < 3; ++s) {
    f[s] = (const float*)d_in[7 * s + 0];
    ia[s] = (const float*)d_in[7 * s + 1];
    w[s] = (const float*)d_in[7 * s + 2];
    b[s] = (const float*)d_in[7 * s + 3];
    im[s] = (const float*)d_in[7 * s + 4];
    wk[s] = (const float*)d_in[7 * s + 5];
    bk[s] = (const float*)d_in[7 * s + 6];
  }
  // workspace: Wp0 90112B | Wp1 180224B | Wp2 360448B | 3x bias 176 f32
  char* ws = (char*)d_ws;
  unsigned short* Wp0 = (unsigned short*)(ws + 0);
  unsigned short* Wp1 = (unsigned short*)(ws + 90112);
  unsigned short* Wp2 = (unsigned short*)(ws + 270336);
  float* bias0 = (float*)(ws + 630784);
  float* bias1 = (float*)(ws + 631488);
  float* bias2 = (float*)(ws + 632192);

  PrepArgs A0 = {w[0], b[0], im[0], ia[0], wk[0], bk[0], Wp0, bias0, 256};
  PrepArgs A1 = {w[1], b[1], im[1], ia[1], wk[1], bk[1], Wp1, bias1, 512};
  PrepArgs A2 = {w[2], b[2], im[2], ia[2], wk[2], bk[2], Wp2, bias2, 1024};
  prep_kernel<<<dim3(176, 3), 64, 0, stream>>>(A0, A1, A2);

  main_kernel<<<1050, 256, 0, stream>>>(f[0], f[1], f[2], Wp0, Wp1, Wp2, bias0, bias1, bias2,
                                        (float*)d_out);
}

// Round 3
// 297.010 us; speedup vs baseline: 1.1506x; 1.1506x over previous
//
#include <hip/hip_runtime.h>
#include <hip/hip_bf16.h>

typedef __attribute__((ext_vector_type(8))) short short8;
typedef __attribute__((ext_vector_type(4))) float floatx4;

__device__ __forceinline__ float sigm(float x) { return 1.0f / (1.0f + __expf(-x)); }

__device__ __forceinline__ unsigned short f2bf(float v) {
  union { __hip_bfloat16 h; unsigned short u; } cv;
  cv.h = __float2bfloat16(v);
  return cv.u;
}

__device__ __forceinline__ void glds16(const void* g, void* l) {
  __builtin_amdgcn_global_load_lds((const __attribute__((address_space(1))) void*)g,
                                   (__attribute__((address_space(3))) void*)l, 16, 0, 0);
}

// ---------------- prep: fold ia/im/bias into padded bf16 weights ----------------
// Combined channel c (0..170): c<18 -> det row c (scaled by im, bias im*(b + W.ia));
//                              c>=18 -> kpt row c-18 (bias bk). Rows 171..191 zero.
struct PrepArgs {
  const float *w, *b, *im, *ia, *wk, *bk;
  unsigned short* Wp;
  float* bias;
  int C;
};

__global__ void prep_kernel(PrepArgs A0, PrepArgs A1, PrepArgs A2) {
  PrepArgs A = (blockIdx.y == 0) ? A0 : (blockIdx.y == 1) ? A1 : A2;
  const int n = blockIdx.x;   // 0..191
  const int t = threadIdx.x;  // 0..63
  const int C = A.C;
  unsigned short* wrow = A.Wp + (size_t)n * C;
  if (n >= 171) {
    for (int k = t; k < C; k += 64) wrow[k] = 0;
    if (t == 0) A.bias[n] = 0.0f;
    return;
  }
  if (n < 18) {
    const float* src = A.w + (size_t)n * C;
    const float sc = A.im[n];
    float dot = 0.0f;
    for (int k = t; k < C; k += 64) {
      float v = src[k];
      dot += v * A.ia[k];
      wrow[k] = f2bf(v * sc);
    }
#pragma unroll
    for (int off = 32; off > 0; off >>= 1) dot += __shfl_down(dot, off);
    if (t == 0) A.bias[n] = sc * (A.b[n] + dot);
  } else {
    const float* src = A.wk + (size_t)(n - 18) * C;
    for (int k = t; k < C; k += 64) wrow[k] = f2bf(src[k]);
    if (t == 0) A.bias[n] = A.bk[n - 18];
  }
}

// ---------------- pipelined fused GEMM (bf16 MFMA) + decode ----------------
// Block = 64 m x 176 n, 4 waves (wave = 16m x 176n). BK = 64.
// A: fp32 gathers -> regs, cvt bf16 -> LDS [64][72]; prefetched ACROSS the barrier
//    (raw s_barrier, manual s_waitcnt vmcnt(16) keeps 16 A-loads in flight).
// B: global_load_lds 16B, XOR-chunk-swizzled LDS [192][64] (no pad, conflict-even).
#define LDS_BYTES 34560  // A 9216 + B 24576 staging; epilogue 32*180*4=23040 reuses

template <int SC, int C, int HW, int W>
__device__ __forceinline__ void gemm_decode(const float* __restrict__ feat,
                                            const unsigned short* __restrict__ Wp,
                                            const float* __restrict__ bias,
                                            float* __restrict__ out, int tile, char* smem) {
  constexpr float STRD = (SC == 0) ? 8.0f : (SC == 1) ? 16.0f : 32.0f;
  constexpr int ZOFF = (SC == 0) ? 0 : (SC == 1) ? 19200 : 24000;
  constexpr int I = C / 64;

  const int t = threadIdx.x;
  const int lane = t & 63;
  const int wv = t >> 6;
  const int l15 = lane & 15;
  const int quad = lane >> 4;

  unsigned short* Alds = (unsigned short*)smem;  // [64][72] bf16
  char* BB = smem + 9216;                        // [192][128B] bf16, XOR-swizzled
  float* Elds = (float*)smem;                    // epilogue [32][180] fp32 (reuse)

  // A staging: thread (lane=row m, wv -> k = wv*16 + 0..15), stride-HW gathers
  const int mA = tile * 64 + lane;
  const int bA = mA / HW;
  const int pA = mA - bA * HW;
  const float* fbase = feat + ((size_t)bA * C + wv * 16) * (size_t)HW + pA;

  // B glds per-lane source mapping (8 rows per instr, chunk XOR row&7)
  const int rsub = lane >> 3;          // row within 8-row group
  const int csw = (lane & 7) ^ rsub;   // swizzled 16B-chunk index
  const char* WpB = (const char*)Wp;

  floatx4 acc[11];
#pragma unroll
  for (int nj = 0; nj < 11; ++nj) acc[nj] = (floatx4){0.f, 0.f, 0.f, 0.f};

  // fragment read bases
  const unsigned short* aRd = Alds + (wv * 16 + l15) * 72 + quad * 8;
  const int c0 = quad ^ (l15 & 7);
  const char* bRd0 = BB + (size_t)l15 * 128 + c0 * 16;
  const char* bRd1 = BB + (size_t)l15 * 128 + (c0 ^ 4) * 16;

  float v[16];
  auto loadA = [&](int it) {
    const float* g = fbase + (size_t)it * 64 * HW;
#pragma unroll
    for (int kk = 0; kk < 16; ++kk) v[kk] = g[(size_t)kk * HW];
  };
  auto writeA = [&]() {
    short8 s0, s1;
#pragma unroll
    for (int j = 0; j < 8; ++j) {
      s0[j] = (short)f2bf(v[j]);
      s1[j] = (short)f2bf(v[j + 8]);
    }
    *(short8*)(Alds + lane * 72 + wv * 16) = s0;
    *(short8*)(Alds + lane * 72 + wv * 16 + 8) = s1;
  };

  loadA(0);
  for (int it = 0; it < I; ++it) {
    asm volatile("s_barrier" ::: "memory");  // LDS free for overwrite (no drain)
    // --- stage B tile via async global->LDS (rows wv*48 .. wv*48+47)
#pragma unroll
    for (int j = 0; j < 6; ++j) {
      const int rowb = wv * 48 + j * 8;
      const void* gsrc = WpB + ((size_t)(rowb + rsub) * C + (size_t)it * 64) * 2 + csw * 16;
      glds16(gsrc, BB + rowb * 128);
    }
    __builtin_amdgcn_sched_barrier(0);  // pin: glds issued before A ops
    // --- write A tile (waits only its own gather regs, glds stays in flight)
    writeA();
    // --- prefetch next A tile across the barrier
    loadA((it + 1 < I) ? it + 1 : it);
    __builtin_amdgcn_sched_barrier(0);  // pin: prefetch issued before waitcnt
    // drain glds(6) + lds writes, keep the 16 A-prefetch loads outstanding
    asm volatile("s_waitcnt vmcnt(16) lgkmcnt(0)\n\ts_barrier" ::: "memory");
    // --- MFMA: wave computes 16m x 176n, overlapping A-prefetch flight
    short8 af0 = *(const short8*)(aRd);
    short8 af1 = *(const short8*)(aRd + 32);
#pragma unroll
    for (int nj = 0; nj < 11; ++nj) {
      short8 b0 = *(const short8*)(bRd0 + (size_t)nj * 2048);
      short8 b1 = *(const short8*)(bRd1 + (size_t)nj * 2048);
      acc[nj] = __builtin_amdgcn_mfma_f32_16x16x32_bf16(af0, b0, acc[nj], 0, 0, 0);
      acc[nj] = __builtin_amdgcn_mfma_f32_16x16x32_bf16(af1, b1, acc[nj], 0, 0, 0);
    }
  }

  // ---------------- epilogue: 2 chunks of 32 rows ----------------
  float bj[11];
#pragma unroll
  for (int nj = 0; nj < 11; ++nj) bj[nj] = bias[nj * 16 + l15];

#pragma unroll
  for (int c = 0; c < 2; ++c) {
    __syncthreads();  // full drain; staging LDS dead -> Elds
    if ((wv >> 1) == c) {
      const int rbase = (wv & 1) * 16 + quad * 4;
#pragma unroll
      for (int nj = 0; nj < 11; ++nj)
#pragma unroll
        for (int r = 0; r < 4; ++r)
          Elds[(rbase + r) * 180 + nj * 16 + l15] = acc[nj][r] + bj[nj];
    }
    __syncthreads();
    if (t < 192) {
      const int task = t >> 1, half = t & 1;
      const int row = task & 31, a = task >> 5;
      const int m = tile * 64 + c * 32 + row;
      const int bb = m / HW;
      const int p = m - bb * HW;
      const float fx = (float)(p % W);
      const float fy = (float)(p / W);
      float* L = Elds + row * 180 + a * 57;
      if (half == 0) {
        float aw, ah;
        if constexpr (SC == 0) {
          aw = (a == 0) ? 19.f : (a == 1) ? 44.f : 38.f;
          ah = (a == 0) ? 27.f : (a == 1) ? 40.f : 94.f;
        } else if constexpr (SC == 1) {
          aw = (a == 0) ? 96.f : (a == 1) ? 86.f : 180.f;
          ah = (a == 0) ? 68.f : (a == 1) ? 152.f : 137.f;
        } else {
          aw = (a == 0) ? 140.f : (a == 1) ? 303.f : 238.f;
          ah = (a == 0) ? 301.f : (a == 1) ? 264.f : 542.f;
        }
        float r0 = L[0], r1 = L[1], r2 = L[2], r3 = L[3], r4 = L[4], r5 = L[5];
        L[0] = (sigm(r0) * 2.f - 0.5f + fx) * STRD;
        L[1] = (sigm(r1) * 2.f - 0.5f + fy) * STRD;
        float tw = sigm(r2) * 2.f;
        L[2] = tw * tw * aw;
        float th = sigm(r3) * 2.f;
        L[3] = th * th * ah;
        L[4] = sigm(r4);
        L[5] = sigm(r5);
#pragma unroll
        for (int kp = 0; kp < 8; ++kp) {
          float kx = L[6 + 3 * kp], ky = L[7 + 3 * kp], kc = L[8 + 3 * kp];
          L[6 + 3 * kp] = (kx * 2.f - 0.5f + fx) * STRD;
          L[7 + 3 * kp] = (ky * 2.f - 0.5f + fy) * STRD;
          L[8 + 3 * kp] = sigm(kc);
        }
      } else {
#pragma unroll
        for (int kp = 8; kp < 17; ++kp) {
          float kx = L[6 + 3 * kp], ky = L[7 + 3 * kp], kc = L[8 + 3 * kp];
          L[6 + 3 * kp] = (kx * 2.f - 0.5f + fx) * STRD;
          L[7 + 3 * kp] = (ky * 2.f - 0.5f + fy) * STRD;
          L[8 + 3 * kp] = sigm(kc);
        }
      }
    }
    __syncthreads();
    for (int i = t; i < 96 * 57; i += 256) {
      int sr = i / 57;
      int j = i - sr * 57;
      int a = sr >> 5, row = sr & 31;
      int m = tile * 64 + c * 32 + row;
      int bb = m / HW;
      int p = m - bb * HW;
      out[((size_t)bb * 25200 + (size_t)(ZOFF + a * HW + p)) * 57 + j] =
          Elds[row * 180 + a * 57 + j];
    }
  }
}

__global__ __launch_bounds__(256, 4) void main_kernel(
    const float* __restrict__ f0, const float* __restrict__ f1, const float* __restrict__ f2,
    const unsigned short* __restrict__ Wp0, const unsigned short* __restrict__ Wp1,
    const unsigned short* __restrict__ Wp2, const float* __restrict__ b0,
    const float* __restrict__ b1, const float* __restrict__ b2, float* __restrict__ out) {
  __shared__ __align__(16) char smem[LDS_BYTES];
  const int bid = blockIdx.x;
  // longest blocks (scale 2, C=1024) first to amortize the tail
  if (bid < 100)
    gemm_decode<2, 1024, 400, 20>(f2, Wp2, b2, out, bid, smem);
  else if (bid < 500)
    gemm_decode<1, 512, 1600, 40>(f1, Wp1, b1, out, bid - 100, smem);
  else
    gemm_decode<0, 256, 6400, 80>(f0, Wp0, b0, out, bid - 500, smem);
}

extern "C" void kernel_launch(void* const* d_in, const int* in_sizes, int n_in, void* d_out,
                              int out_size, void* d_ws, size_t ws_size, hipStream_t stream) {
  const float *f[3], *ia[3], *w[3], *b[3], *im[3], *wk[3], *bk[3];
  for (int s = 0; s < 3; ++s) {
    f[s] = (const float*)d_in[7 * s + 0];
    ia[s] = (const float*)d_in[7 * s + 1];
    w[s] = (const float*)d_in[7 * s + 2];
    b[s] = (const float*)d_in[7 * s + 3];
    im[s] = (const float*)d_in[7 * s + 4];
    wk[s] = (const float*)d_in[7 * s + 5];
    bk[s] = (const float*)d_in[7 * s + 6];
  }
  // workspace: Wp[s] has 192 rows (rows 176..191 zero, for uniform glds coverage)
  // Wp0 98304B | Wp1 196608B | Wp2 393216B | 3x bias 192 f32
  char* ws = (char*)d_ws;
  unsigned short* Wp0 = (unsigned short*)(ws + 0);
  unsigned short* Wp1 = (unsigned short*)(ws + 98304);
  unsigned short* Wp2 = (unsigned short*)(ws + 294912);
  float* bias0 = (float*)(ws + 688128);
  float* bias1 = (float*)(ws + 688896);
  float* bias2 = (float*)(ws + 689664);

  PrepArgs A0 = {w[0], b[0], im[0], ia[0], wk[0], bk[0], Wp0, bias0, 256};
  PrepArgs A1 = {w[1], b[1], im[1], ia[1], wk[1], bk[1], Wp1, bias1, 512};
  PrepArgs A2 = {w[2], b[2], im[2], ia[2], wk[2], bk[2], Wp2, bias2, 1024};
  prep_kernel<<<dim3(192, 3), 64, 0, stream>>>(A0, A1, A2);

  main_kernel<<<2100, 256, 0, stream>>>(f[0], f[1], f[2], Wp0, Wp1, Wp2, bias0, bias1, bias2,
                                        (float*)d_out);
}